// Round 7
// baseline (510.981 us; speedup 1.0000x reference)
//
#include <hip/hip_runtime.h>

typedef __bf16  bf16x8 __attribute__((ext_vector_type(8)));
typedef __bf16  bf16x4 __attribute__((ext_vector_type(4)));
typedef short   s16x4  __attribute__((ext_vector_type(4)));
typedef float   f32x4  __attribute__((ext_vector_type(4)));

__device__ __forceinline__ unsigned short f2bf(float f) {
    union { float f; unsigned int u; } v; v.f = f;
    unsigned int u = v.u;
    unsigned int r = (u + 0x7fffu + ((u >> 16) & 1u)) >> 16;   // RNE
    return (unsigned short)r;
}

// pack two floats -> two bf16 in one dword
__device__ __forceinline__ unsigned int pkbf(float lo, float hi) {
    union { float f; unsigned int u; } a, b; a.f = lo; b.f = hi;
    return __builtin_amdgcn_perm(b.u + 0x8000u, a.u + 0x8000u, 0x07060302u);
}

// 8 fp32 -> bf16x8 (memory order, k ascending)
__device__ __forceinline__ bf16x8 pack8(float4 lo, float4 hi) {
    union { unsigned int u[4]; bf16x8 v; } r;
    r.u[0] = pkbf(lo.x, lo.y); r.u[1] = pkbf(lo.z, lo.w);
    r.u[2] = pkbf(hi.x, hi.y); r.u[3] = pkbf(hi.z, hi.w);
    return r.v;
}

// 2^x without OCML's denorm-range fixup (inputs bounded ~|10|).
// NOTE: must be the builtin (compiler-known trans op) — bare inline-asm
// v_exp_f32 violates the trans->VALU wait-state hazard (v4's nondet bug).
__device__ __forceinline__ float fexp2(float x) {
#if __has_builtin(__builtin_amdgcn_exp2f)
    return __builtin_amdgcn_exp2f(x);
#else
    float r; asm("v_exp_f32 %0, %1\n\ts_nop 1" : "=v"(r) : "v"(x)); return r;
#endif
}

// async global->LDS, 16B per lane. LDS dest = wave-uniform base + lane*16.
__device__ __forceinline__ void gld_lds16(const unsigned short* g, unsigned short* l) {
    auto gp = (const __attribute__((address_space(1))) unsigned int*)(const void*)g;
    auto lp = (__attribute__((address_space(3))) unsigned int*)(unsigned int)(unsigned long long)(void*)l;
    __builtin_amdgcn_global_load_lds(gp, lp, 16, 0, 0);
}

// 16x16x16 bf16 MFMA (K=16): B-fragment k-grouping (q*4+e) matches the
// 16x16 C/D layout (row=q*4+r) exactly -> S^T fragment feeds PV directly.
__device__ __forceinline__ f32x4 mfma16(bf16x4 a, bf16x4 b, f32x4 c) {
#if __has_builtin(__builtin_amdgcn_mfma_f32_16x16x16_bf16)
    return __builtin_amdgcn_mfma_f32_16x16x16_bf16(a, b, c, 0, 0, 0);
#elif __has_builtin(__builtin_amdgcn_mfma_f32_16x16x16bf16_1k)
    union U { bf16x4 h; s16x4 s; } ua, ub; ua.h = a; ub.h = b;
    return __builtin_amdgcn_mfma_f32_16x16x16bf16_1k(ua.s, ub.s, c, 0, 0, 0);
#else
    asm("v_mfma_f32_16x16x16_bf16 %0, %1, %2, %0" : "+v"(c) : "v"(a), "v"(b));
    return c;
#endif
}

// 4 weight matrices (1M fp32 each) -> bf16, one launch
__global__ void cast4_kernel(const float* __restrict__ a, const float* __restrict__ b,
                             const float* __restrict__ c, const float* __restrict__ d,
                             unsigned short* __restrict__ dst) {
    int sel = blockIdx.x >> 10;
    int off4 = (blockIdx.x & 1023) * 256 + threadIdx.x;
    const float* src = sel == 0 ? a : sel == 1 ? b : sel == 2 ? c : d;
    float4 f = ((const float4*)src)[off4];
    uint2 pk; pk.x = pkbf(f.x, f.y); pk.y = pkbf(f.z, f.w);
    ((uint2*)(dst + (size_t)sel * 1048576))[off4] = pk;
}

// Fused QKV projection, v6: NO LDS, NO BARRIERS — direct register fragments.
// v5 diagnosis: reg->LDS A-staging put an HBM-latency vmcnt stall inside the
// barrier-coupled body (MfmaUtil 17.6%). Here each lane loads its own MFMA
// fragment straight from global: A fragment rows are shared by only 2 waves
// (wc pair, same block) -> L1 dedups; B likewise (wr pair). One-deep static
// double-buffer prefetch gives loads a full sub-iter window; 12 waves/CU of
// barrier-free TLP hide the rest.
// z = blockIdx.z selects {values->V^T, keys->K, queries->Q(scaled)}.
// grid (64, 8, 3): bid%8 = x%8 -> all (y,z) for an m-tile share an XCD.
__global__ __launch_bounds__(256, 3)
void gemm_qkv(const float* __restrict__ V32, const float* __restrict__ K32,
              const float* __restrict__ Q32, const unsigned short* __restrict__ W,
              unsigned short* __restrict__ Vtb, unsigned short* __restrict__ Kb,
              unsigned short* __restrict__ Qb, float qscale)
{
    const int z = blockIdx.z;
    const float* A32 = z == 0 ? V32 : z == 1 ? K32 : Q32;
    const unsigned short* Bt = W + (size_t)z * 1048576;
    unsigned short* dst = z == 0 ? Vtb : z == 1 ? Kb : Qb;
    const float a_scale = z == 2 ? qscale : 1.f;

    const int t    = threadIdx.x;
    const int lane = t & 63;
    const int w    = t >> 6;
    const int q    = lane >> 4;
    const int ln   = lane & 15;
    const int wr   = w >> 1, wc = w & 1;
    const int m0   = blockIdx.x * 128;
    const int n0   = blockIdx.y * 128;

    // per-lane fragment row pointers (same (row, k) map as the old LDS reads:
    // af[i] = A[m0+wr*64+i*16+ln][k0+q*8..+7], bfr[jj] = B[n0+wc*64+jj*16+ln][...])
    const float* Ar0 = A32 + (size_t)(m0 + wr * 64 +  0 + ln) * 1024 + q * 8;
    const float* Ar1 = A32 + (size_t)(m0 + wr * 64 + 16 + ln) * 1024 + q * 8;
    const float* Ar2 = A32 + (size_t)(m0 + wr * 64 + 32 + ln) * 1024 + q * 8;
    const float* Ar3 = A32 + (size_t)(m0 + wr * 64 + 48 + ln) * 1024 + q * 8;
    const unsigned short* Br0 = Bt + (size_t)(n0 + wc * 64 +  0 + ln) * 1024 + q * 8;
    const unsigned short* Br1 = Bt + (size_t)(n0 + wc * 64 + 16 + ln) * 1024 + q * 8;
    const unsigned short* Br2 = Bt + (size_t)(n0 + wc * 64 + 32 + ln) * 1024 + q * 8;
    const unsigned short* Br3 = Bt + (size_t)(n0 + wc * 64 + 48 + ln) * 1024 + q * 8;

    f32x4 acc[4][4];
    const f32x4 zz = {0.f, 0.f, 0.f, 0.f};
#pragma unroll
    for (int i = 0; i < 4; ++i)
#pragma unroll
        for (int j = 0; j < 4; ++j) acc[i][j] = zz;

    auto LOADA = [&](float4* la, int j) {
        la[0] = *(const float4*)(Ar0 + j * 32); la[1] = *(const float4*)(Ar0 + j * 32 + 4);
        la[2] = *(const float4*)(Ar1 + j * 32); la[3] = *(const float4*)(Ar1 + j * 32 + 4);
        la[4] = *(const float4*)(Ar2 + j * 32); la[5] = *(const float4*)(Ar2 + j * 32 + 4);
        la[6] = *(const float4*)(Ar3 + j * 32); la[7] = *(const float4*)(Ar3 + j * 32 + 4);
    };
    auto LOADB = [&](bf16x8* bf, int j) {
        bf[0] = *(const bf16x8*)(Br0 + j * 32);
        bf[1] = *(const bf16x8*)(Br1 + j * 32);
        bf[2] = *(const bf16x8*)(Br2 + j * 32);
        bf[3] = *(const bf16x8*)(Br3 + j * 32);
    };
    auto STEP = [&](const float4* la, const bf16x8* bf) {
        bf16x8 af[4];
#pragma unroll
        for (int i = 0; i < 4; ++i) af[i] = pack8(la[2 * i], la[2 * i + 1]);
#pragma unroll
        for (int i = 0; i < 4; ++i)
#pragma unroll
            for (int jj = 0; jj < 4; ++jj)
                acc[i][jj] = __builtin_amdgcn_mfma_f32_16x16x32_bf16(af[i], bf[jj], acc[i][jj], 0, 0, 0);
    };

    // one-deep prefetch, static buffers (no runtime-indexed arrays)
    float4 la[8];
    bf16x8 bfA[4], bfB[4];
    LOADA(la, 0);
    LOADB(bfA, 0);
#pragma unroll
    for (int j = 0; j < 32; j += 2) {
        // sub-iter j: la = A(j), bfA = B(j)
        {
            bf16x8 af[4];
#pragma unroll
            for (int i = 0; i < 4; ++i) af[i] = pack8(la[2 * i], la[2 * i + 1]);  // frees la
            LOADB(bfB, j + 1);
            LOADA(la, j + 1);
#pragma unroll
            for (int i = 0; i < 4; ++i)
#pragma unroll
                for (int jj = 0; jj < 4; ++jj)
                    acc[i][jj] = __builtin_amdgcn_mfma_f32_16x16x32_bf16(af[i], bfA[jj], acc[i][jj], 0, 0, 0);
        }
        // sub-iter j+1: la = A(j+1), bfB = B(j+1)
        {
            bf16x8 af[4];
#pragma unroll
            for (int i = 0; i < 4; ++i) af[i] = pack8(la[2 * i], la[2 * i + 1]);
            if (j + 2 < 32) { LOADB(bfA, j + 2); LOADA(la, j + 2); }
#pragma unroll
            for (int i = 0; i < 4; ++i)
#pragma unroll
                for (int jj = 0; jj < 4; ++jj)
                    acc[i][jj] = __builtin_amdgcn_mfma_f32_16x16x32_bf16(af[i], bfB[jj], acc[i][jj], 0, 0, 0);
        }
    }

    // epilogue: C/D layout row=(lane>>4)*4+r, col=lane&15. z-uniform branches.
#pragma unroll
    for (int i = 0; i < 4; ++i) {
#pragma unroll
        for (int jj = 0; jj < 4; ++jj) {
            f32x4 c = acc[i][jj];
            int mb = m0 + wr * 64 + i * 16 + q * 4;
            int nn = n0 + wc * 64 + jj * 16 + ln;
            if (z == 0) {          // V^T scatter [N,H,D,S], packed 8B stores
                int b = mb >> 11, s = mb & 2047, h = nn >> 6, d = nn & 63;
                uint2 pk;
                pk.x = pkbf(c[0], c[1]);
                pk.y = pkbf(c[2], c[3]);
                size_t idx = (((size_t)(b * 16 + h) * 64) + d) * 2048 + s;
                *(uint2*)&dst[idx] = pk;
            } else {               // K/Q scatter [N,H,S,D]
#pragma unroll
                for (int r = 0; r < 4; ++r) {
                    int m = mb + r;
                    float val = c[r] * a_scale;
                    int b = m >> 11, s = m & 2047, h = nn >> 6, d = nn & 63;
                    size_t idx = (((size_t)(b * 16 + h) * 2048) + s) * 64 + d;
                    dst[idx] = f2bf(val);
                }
            }
        }
    }
}

// C = A(M x K) * Bt(N x K)^T, bf16 in, K=1024, N=1024. Output proj only:
// dst fp32 [M,N] + bias. Pipelined gld_lds staging (proven structure).
template <int MODE>
__global__ __launch_bounds__(256, 3)
void gemm_bt(const unsigned short* __restrict__ A, const unsigned short* __restrict__ Bt,
             void* __restrict__ dst, const float* __restrict__ bias, float a_scale)
{
    constexpr int K = 1024;
    __shared__ unsigned short As[2][4096];
    __shared__ unsigned short Bs[2][4096];

    const int t    = threadIdx.x;
    const int lane = t & 63;
    const int w    = t >> 6;
    const int q    = lane >> 4;
    const int ln   = lane & 15;
    const int wr   = w >> 1, wc = w & 1;
    const int m0   = blockIdx.x * 128;
    const int n0   = blockIdx.y * 128;
    const int srow = lane >> 2;
    const int scol = (lane & 3) * 8;

    f32x4 acc[4][4];
    const f32x4 zz = {0.f, 0.f, 0.f, 0.f};
#pragma unroll
    for (int i = 0; i < 4; ++i)
#pragma unroll
        for (int j = 0; j < 4; ++j) acc[i][j] = zz;

    auto stage = [&](int k0, int p) {
#pragma unroll
        for (int c = 0; c < 2; ++c) {
            int u = w * 2 + c;
            gld_lds16(A  + (size_t)(m0 + u * 16 + srow) * K + k0 + scol, &As[p][u * 512]);
            gld_lds16(Bt + (size_t)(n0 + u * 16 + srow) * K + k0 + scol, &Bs[p][u * 512]);
        }
    };

    stage(0, 0);
    for (int j = 0; j < 32; ++j) {
        __syncthreads();
        if (j < 31) stage((j + 1) * 32, (j + 1) & 1);
        const int p = j & 1;
        bf16x8 af[4], bfr[4];
#pragma unroll
        for (int i = 0; i < 4; ++i)
            af[i] = *(const bf16x8*)&As[p][(wr * 64 + i * 16 + ln) * 32 + q * 8];
#pragma unroll
        for (int jj = 0; jj < 4; ++jj)
            bfr[jj] = *(const bf16x8*)&Bs[p][(wc * 64 + jj * 16 + ln) * 32 + q * 8];
#pragma unroll
        for (int i = 0; i < 4; ++i)
#pragma unroll
            for (int jj = 0; jj < 4; ++jj)
                acc[i][jj] = __builtin_amdgcn_mfma_f32_16x16x32_bf16(af[i], bfr[jj], acc[i][jj], 0, 0, 0);
    }

#pragma unroll
    for (int i = 0; i < 4; ++i) {
#pragma unroll
        for (int j = 0; j < 4; ++j) {
            f32x4 c = acc[i][j];
            int mb = m0 + wr * 64 + i * 16 + q * 4;
            int nn = n0 + wc * 64 + j * 16 + ln;
#pragma unroll
            for (int r = 0; r < 4; ++r) {
                int m = mb + r;
                float val = c[r] * a_scale;
                ((float*)dst)[(size_t)m * 1024 + nn] = val + bias[nn];
            }
        }
    }
}

// Flash attention, transposed-S, no online max (|s*log2e| bounded ~3).
// 64-key tiles, double-buffered K/V staging, ONE barrier per iter.
// Builtin exp2 (trans-op hazard safe); l-reduction deferred out of K-loop;
// P register-resident (16x16x16 PV); swizzled K/V LDS.
// S^T = K Q^T ; O^T = V^T P^T. Q pre-scaled by log2e/sqrt(E).
// Q,K [head][s][d]; Vt [head][d][s]. O bf16 [N,S,E]. grid (64 heads, 16 qt).
__global__ __launch_bounds__(256, 4)
void attn_kernel(const unsigned short* __restrict__ Q, const unsigned short* __restrict__ Kg,
                 const unsigned short* __restrict__ Vt, unsigned short* __restrict__ Og)
{
    __shared__ __align__(16) unsigned short Ks[2][4096];   // 2 x (2 panels of 64rows x 32)
    __shared__ __align__(16) unsigned short Vs[2][4096];   // 2 x (2 panels of 64d  x 32)

    const int t    = threadIdx.x;
    const int lane = t & 63;
    const int w    = t >> 6;
    const int q    = lane >> 4;
    const int ln   = lane & 15;
    const int xs   = (ln >> 1) & 3;      // read-side swizzle: slot ^= (row>>1)&3, row%16 = ln
    const int head = blockIdx.x;
    const int qt   = blockIdx.y;

    const unsigned short* Qh  = Q  + (size_t)head * 2048 * 64;
    const unsigned short* Kh  = Kg + (size_t)head * 2048 * 64;
    const unsigned short* Vth = Vt + (size_t)head * 64 * 2048;

    const int srow = lane >> 2;
    // staging writes are linear (lane*16B): row = lane>>2, phys slot = lane&3.
    // phys slot must hold logical slot (lane&3)^sw(row), sw(row)=(row>>1)&3=(lane>>3)&3
    const int ssw  = ((lane & 3) ^ ((lane >> 3) & 3)) * 8;

    // Q as B-fragments (qrow in lanes, k = d), resident all kernel
    bf16x8 qf[2][2];
    const int rowb = qt * 128 + w * 32;
#pragma unroll
    for (int ti = 0; ti < 2; ++ti)
#pragma unroll
        for (int kc = 0; kc < 2; ++kc)
            qf[ti][kc] = *(const bf16x8*)&Qh[(size_t)(rowb + ti * 16 + ln) * 64 + kc * 32 + q * 8];

    const f32x4 zz = {0.f, 0.f, 0.f, 0.f};
    f32x4 oa[2][4];
#pragma unroll
    for (int ti = 0; ti < 2; ++ti)
#pragma unroll
        for (int dt = 0; dt < 4; ++dt) oa[ti][dt] = zz;
    float l_s[2] = {0.f, 0.f};           // lane-partial; cross-q reduce deferred

    // stage 64-key tile j into buffer p (source column pre-swizzled)
    auto stage = [&](int j, int p) {
#pragma unroll
        for (int c = 0; c < 2; ++c) {
            int u = w * 2 + c;                 // 0..7
            int kc = u >> 2, rg = u & 3;
            gld_lds16(Kh + (size_t)(j * 64 + rg * 16 + srow) * 64 + kc * 32 + ssw,
                      &Ks[p][kc * 2048 + rg * 512]);
            gld_lds16(Vth + (size_t)(rg * 16 + srow) * 2048 + j * 64 + kc * 32 + ssw,
                      &Vs[p][kc * 2048 + rg * 512]);
        }
    };

    stage(0, 0);
    for (int j = 0; j < 32; ++j) {
        __syncthreads();                       // drains gld(j); all reads of buf (j+1)&1 done
        if (j < 31) stage(j + 1, (j + 1) & 1);
        const int p = j & 1;

        // ---- S^T = K Q^T, per 16-key tile; exp + cvt immediately (short sa life) ----
        bf16x4 pb[4][2];                       // P^T B-fragments, in registers
        float rs0 = 0.f, rs1 = 0.f;
#pragma unroll
        for (int kt = 0; kt < 4; ++kt) {
            f32x4 s0 = zz, s1 = zz;
#pragma unroll
            for (int kc = 0; kc < 2; ++kc) {
                bf16x8 ka = *(const bf16x8*)&Ks[p][kc * 2048 + (kt * 16 + ln) * 32 + ((q ^ xs) * 8)];
                s0 = __builtin_amdgcn_mfma_f32_16x16x32_bf16(ka, qf[0][kc], s0, 0, 0, 0);
                s1 = __builtin_amdgcn_mfma_f32_16x16x32_bf16(ka, qf[1][kc], s1, 0, 0, 0);
            }
            {
                float a0 = fexp2(s0[0]), a1 = fexp2(s0[1]), a2 = fexp2(s0[2]), a3 = fexp2(s0[3]);
                rs0 += (a0 + a1) + (a2 + a3);
                f32x4 pe = {a0, a1, a2, a3};
                pb[kt][0] = __builtin_convertvector(pe, bf16x4);
            }
            {
                float b0 = fexp2(s1[0]), b1 = fexp2(s1[1]), b2 = fexp2(s1[2]), b3 = fexp2(s1[3]);
                rs1 += (b0 + b1) + (b2 + b3);
                f32x4 pe = {b0, b1, b2, b3};
                pb[kt][1] = __builtin_convertvector(pe, bf16x4);
            }
        }
        l_s[0] += rs0;
        l_s[1] += rs1;

        // ---- O^T += V^T P^T, K=16 MFMAs, P from registers ----
#pragma unroll
        for (int kt = 0; kt < 4; ++kt) {
            const int kc = kt >> 1;
            // V^T 8B read: keys kt*16 + q*4 .. +3 -> 16B slot s=(kt&1)*2+(q>>1), half q&1
            const int so = ((((kt & 1) * 2 + (q >> 1)) ^ xs) * 8) + (q & 1) * 4;
            bf16x4 va[4];
#pragma unroll
            for (int dt = 0; dt < 4; ++dt)
                va[dt] = *(const bf16x4*)&Vs[p][kc * 2048 + (dt * 16 + ln) * 32 + so];
#pragma unroll
            for (int dt = 0; dt < 4; ++dt) {
                oa[0][dt] = mfma16(va[dt], pb[kt][0], oa[0][dt]);
                oa[1][dt] = mfma16(va[dt], pb[kt][1], oa[1][dt]);
            }
        }
    }

    // deferred cross-q reduction (lanes differ in bits 4,5 of lane id)
    l_s[0] += __shfl_xor(l_s[0], 16); l_s[0] += __shfl_xor(l_s[0], 32);
    l_s[1] += __shfl_xor(l_s[1], 16); l_s[1] += __shfl_xor(l_s[1], 32);

    // ---- finalize: O = (O^T)^T / l, packed 8B stores ----
    const int n = head >> 4;
    const int hbase = (head & 15) * 64;
#pragma unroll
    for (int ti = 0; ti < 2; ++ti) {
        float inv = 1.f / l_s[ti];
        int sr = qt * 128 + w * 32 + ti * 16 + ln;
        size_t base = ((size_t)n * 2048 + sr) * 1024 + hbase;
#pragma unroll
        for (int dt = 0; dt < 4; ++dt) {
            uint2 pk;
            pk.x = pkbf(oa[ti][dt][0] * inv, oa[ti][dt][1] * inv);
            pk.y = pkbf(oa[ti][dt][2] * inv, oa[ti][dt][3] * inv);
            *(uint2*)&Og[base + dt * 16 + q * 4] = pk;
        }
    }
}

extern "C" void kernel_launch(void* const* d_in, const int* in_sizes, int n_in,
                              void* d_out, int out_size, void* d_ws, size_t ws_size,
                              hipStream_t stream)
{
    (void)in_sizes; (void)n_in; (void)out_size; (void)ws_size;
    const float* values  = (const float*)d_in[0];
    const float* keys    = (const float*)d_in[1];
    const float* queries = (const float*)d_in[2];
    const float* Wv = (const float*)d_in[3];
    const float* Wk = (const float*)d_in[4];
    const float* Wq = (const float*)d_in[5];
    const float* Wo = (const float*)d_in[6];
    const float* bo = (const float*)d_in[7];
    float* out = (float*)d_out;

    unsigned short* ws   = (unsigned short*)d_ws;
    unsigned short* Wo_b = ws + 3145728;          // weights: ws + z*1M (z=0..2), Wo at 3M
    unsigned short* Ob   = ws + 4194304;          // 8M: attn output
    unsigned short* Qb   = ws + 12582912;         // 8M each
    unsigned short* Kb   = Qb + 8388608;
    unsigned short* Vtb  = Kb + 8388608;          // total 36M shorts = 72 MB

    const float qscale = 1.4426950408889634f / 32.f;   // log2(e)/sqrt(E)
    dim3 b(256);

    cast4_kernel<<<4096, b, 0, stream>>>(Wv, Wk, Wq, Wo, ws);
    gemm_qkv<<<dim3(64, 8, 3), b, 0, stream>>>(values, keys, queries, ws, Vtb, Kb, Qb, qscale);
    attn_kernel<<<dim3(64, 16), b, 0, stream>>>(Qb, Kb, Vtb, Ob);
    gemm_bt<2><<<dim3(64, 8), b, 0, stream>>>(Ob, Wo_b, out, bo, 1.f);
}

// Round 8
// 324.454 us; speedup vs baseline: 1.5749x; 1.5749x over previous
//
#include <hip/hip_runtime.h>

typedef __bf16  bf16x8 __attribute__((ext_vector_type(8)));
typedef __bf16  bf16x4 __attribute__((ext_vector_type(4)));
typedef short   s16x4  __attribute__((ext_vector_type(4)));
typedef float   f32x4  __attribute__((ext_vector_type(4)));

__device__ __forceinline__ unsigned short f2bf(float f) {
    union { float f; unsigned int u; } v; v.f = f;
    unsigned int u = v.u;
    unsigned int r = (u + 0x7fffu + ((u >> 16) & 1u)) >> 16;   // RNE
    return (unsigned short)r;
}

// pack two floats -> two bf16 in one dword
__device__ __forceinline__ unsigned int pkbf(float lo, float hi) {
    union { float f; unsigned int u; } a, b; a.f = lo; b.f = hi;
    return __builtin_amdgcn_perm(b.u + 0x8000u, a.u + 0x8000u, 0x07060302u);
}

// 2^x without OCML's denorm-range fixup (inputs bounded ~|10|).
// NOTE: must be the builtin (compiler-known trans op) — bare inline-asm
// v_exp_f32 violates the trans->VALU wait-state hazard (v4's nondet bug).
__device__ __forceinline__ float fexp2(float x) {
#if __has_builtin(__builtin_amdgcn_exp2f)
    return __builtin_amdgcn_exp2f(x);
#else
    float r; asm("v_exp_f32 %0, %1\n\ts_nop 1" : "=v"(r) : "v"(x)); return r;
#endif
}

// async global->LDS, 16B per lane. LDS dest = wave-uniform base + lane*16.
__device__ __forceinline__ void gld_lds16(const unsigned short* g, unsigned short* l) {
    auto gp = (const __attribute__((address_space(1))) unsigned int*)(const void*)g;
    auto lp = (__attribute__((address_space(3))) unsigned int*)(unsigned int)(unsigned long long)(void*)l;
    __builtin_amdgcn_global_load_lds(gp, lp, 16, 0, 0);
}

// 16x16x16 bf16 MFMA (K=16): B-fragment k-grouping (q*4+e) matches the
// 16x16 C/D layout (row=q*4+r) exactly -> S^T fragment feeds PV directly.
__device__ __forceinline__ f32x4 mfma16(bf16x4 a, bf16x4 b, f32x4 c) {
#if __has_builtin(__builtin_amdgcn_mfma_f32_16x16x16_bf16)
    return __builtin_amdgcn_mfma_f32_16x16x16_bf16(a, b, c, 0, 0, 0);
#elif __has_builtin(__builtin_amdgcn_mfma_f32_16x16x16bf16_1k)
    union U { bf16x4 h; s16x4 s; } ua, ub; ua.h = a; ub.h = b;
    return __builtin_amdgcn_mfma_f32_16x16x16bf16_1k(ua.s, ub.s, c, 0, 0, 0);
#else
    asm("v_mfma_f32_16x16x16_bf16 %0, %1, %2, %0" : "+v"(c) : "v"(a), "v"(b));
    return c;
#endif
}

// 4 weight matrices (1M fp32 each) -> bf16, one launch
__global__ void cast4_kernel(const float* __restrict__ a, const float* __restrict__ b,
                             const float* __restrict__ c, const float* __restrict__ d,
                             unsigned short* __restrict__ dst) {
    int sel = blockIdx.x >> 10;
    int off4 = (blockIdx.x & 1023) * 256 + threadIdx.x;
    const float* src = sel == 0 ? a : sel == 1 ? b : sel == 2 ? c : d;
    float4 f = ((const float4*)src)[off4];
    uint2 pk; pk.x = pkbf(f.x, f.y); pk.y = pkbf(f.z, f.w);
    ((uint2*)(dst + (size_t)sel * 1048576))[off4] = pk;
}

// Fused QKV projection, v7: v5's LDS-staged structure + 2-DEEP A prefetch.
// v5 stall: loadA(j+1) issued after sync_j, consumed by writeA at END of
// phase j -> window ~1 compute body (~250cyc) < L2 latency. v6 (no-LDS
// direct fragments) was worse: latency-bound at MfmaUtil 7%.
// Here: two static reg buffers; phase j = {sync; stageB(j+1); writeA(data
// j+1, loaded 1.5 phases ago); loadA(j+3); compute(j)}. laA holds odd
// k-steps, laB even (static via 2x unroll — no runtime-indexed reg arrays).
// z = blockIdx.z selects {values->V^T, keys->K, queries->Q(scaled)}.
// grid (64, 8, 3): bid%8 = x%8 -> all (y,z) for an m-tile share an XCD.
__global__ __launch_bounds__(256, 3)
void gemm_qkv(const float* __restrict__ V32, const float* __restrict__ K32,
              const float* __restrict__ Q32, const unsigned short* __restrict__ W,
              unsigned short* __restrict__ Vtb, unsigned short* __restrict__ Kb,
              unsigned short* __restrict__ Qb, float qscale)
{
    constexpr int K = 1024;
    __shared__ unsigned short As[2][4096];
    __shared__ unsigned short Bs[2][4096];

    const int z = blockIdx.z;
    const float* A32 = z == 0 ? V32 : z == 1 ? K32 : Q32;
    const unsigned short* Bt = W + (size_t)z * 1048576;
    unsigned short* dst = z == 0 ? Vtb : z == 1 ? Kb : Qb;
    const float a_scale = z == 2 ? qscale : 1.f;

    const int t    = threadIdx.x;
    const int lane = t & 63;
    const int w    = t >> 6;
    const int q    = lane >> 4;
    const int ln   = lane & 15;
    const int wr   = w >> 1, wc = w & 1;
    const int m0   = blockIdx.x * 128;
    const int n0   = blockIdx.y * 128;
    const int srow = lane >> 2;
    const int scol = (lane & 3) * 8;

    f32x4 acc[4][4];
    const f32x4 zz = {0.f, 0.f, 0.f, 0.f};
#pragma unroll
    for (int i = 0; i < 4; ++i)
#pragma unroll
        for (int j = 0; j < 4; ++j) acc[i][j] = zz;

    // A fp32 -> regs (16 floats/lane). Same (row, col8) map as bf16 staging.
    auto loadA = [&](int k0, float4* fa) {
#pragma unroll
        for (int c = 0; c < 2; ++c) {
            int u = w * 2 + c;
            const float* src = A32 + (size_t)(m0 + u * 16 + srow) * K + k0 + scol;
            fa[c * 2]     = *(const float4*)src;
            fa[c * 2 + 1] = *(const float4*)(src + 4);
        }
    };
    auto writeA = [&](const float4* fa, int p) {
#pragma unroll
        for (int c = 0; c < 2; ++c) {
            int u = w * 2 + c;
            uint4 pk;
            pk.x = pkbf(fa[c * 2].x,     fa[c * 2].y);
            pk.y = pkbf(fa[c * 2].z,     fa[c * 2].w);
            pk.z = pkbf(fa[c * 2 + 1].x, fa[c * 2 + 1].y);
            pk.w = pkbf(fa[c * 2 + 1].z, fa[c * 2 + 1].w);
            *(uint4*)&As[p][u * 512 + lane * 8] = pk;     // lane*16B, linear
        }
    };
    auto stageB = [&](int k0, int p) {
#pragma unroll
        for (int c = 0; c < 2; ++c) {
            int u = w * 2 + c;
            gld_lds16(Bt + (size_t)(n0 + u * 16 + srow) * K + k0 + scol, &Bs[p][u * 512]);
        }
    };
    auto compute = [&](int p) {
        bf16x8 af[4], bfr[4];
#pragma unroll
        for (int i = 0; i < 4; ++i)
            af[i] = *(const bf16x8*)&As[p][(wr * 64 + i * 16 + ln) * 32 + q * 8];
#pragma unroll
        for (int jj = 0; jj < 4; ++jj)
            bfr[jj] = *(const bf16x8*)&Bs[p][(wc * 64 + jj * 16 + ln) * 32 + q * 8];
#pragma unroll
        for (int i = 0; i < 4; ++i)
#pragma unroll
            for (int jj = 0; jj < 4; ++jj)
                acc[i][jj] = __builtin_amdgcn_mfma_f32_16x16x32_bf16(af[i], bfr[jj], acc[i][jj], 0, 0, 0);
    };

    float4 laA[4], laB[4];
    // prologue: buf0 = data0; laA = data1 (write @ phase0); laB = data2 (@ phase1)
    loadA(0, laA);
    stageB(0, 0);
    writeA(laA, 0);
    loadA(32, laA);
    loadA(64, laB);

    for (int j = 0; j < 32; j += 2) {
        // even phase j: compute buf0; prep buf1 with laA(data j+1); reload laA <- j+3
        __syncthreads();                       // drains stageB+writeA for buf0
        if (j + 1 < 32) { stageB((j + 1) * 32, 1); writeA(laA, 1); }
        if (j + 3 < 32) loadA((j + 3) * 32, laA);
        compute(0);
        // odd phase j+1: compute buf1; prep buf0 with laB(data j+2); reload laB <- j+4
        __syncthreads();
        if (j + 2 < 32) { stageB((j + 2) * 32, 0); writeA(laB, 0); }
        if (j + 4 < 32) loadA((j + 4) * 32, laB);
        compute(1);
    }

    // epilogue: C/D layout row=(lane>>4)*4+r, col=lane&15. z-uniform branches.
#pragma unroll
    for (int i = 0; i < 4; ++i) {
#pragma unroll
        for (int jj = 0; jj < 4; ++jj) {
            f32x4 c = acc[i][jj];
            int mb = m0 + wr * 64 + i * 16 + q * 4;
            int nn = n0 + wc * 64 + jj * 16 + ln;
            if (z == 0) {          // V^T scatter [N,H,D,S], packed 8B stores
                int b = mb >> 11, s = mb & 2047, h = nn >> 6, d = nn & 63;
                uint2 pk;
                pk.x = pkbf(c[0], c[1]);
                pk.y = pkbf(c[2], c[3]);
                size_t idx = (((size_t)(b * 16 + h) * 64) + d) * 2048 + s;
                *(uint2*)&dst[idx] = pk;
            } else {               // K/Q scatter [N,H,S,D]
#pragma unroll
                for (int r = 0; r < 4; ++r) {
                    int m = mb + r;
                    float val = c[r] * a_scale;
                    int b = m >> 11, s = m & 2047, h = nn >> 6, d = nn & 63;
                    size_t idx = (((size_t)(b * 16 + h) * 2048) + s) * 64 + d;
                    dst[idx] = f2bf(val);
                }
            }
        }
    }
}

// C = A(M x K) * Bt(N x K)^T, bf16 in, K=1024, N=1024. Output proj only:
// dst fp32 [M,N] + bias. Pipelined gld_lds staging (proven structure).
template <int MODE>
__global__ __launch_bounds__(256, 3)
void gemm_bt(const unsigned short* __restrict__ A, const unsigned short* __restrict__ Bt,
             void* __restrict__ dst, const float* __restrict__ bias, float a_scale)
{
    constexpr int K = 1024;
    __shared__ unsigned short As[2][4096];
    __shared__ unsigned short Bs[2][4096];

    const int t    = threadIdx.x;
    const int lane = t & 63;
    const int w    = t >> 6;
    const int q    = lane >> 4;
    const int ln   = lane & 15;
    const int wr   = w >> 1, wc = w & 1;
    const int m0   = blockIdx.x * 128;
    const int n0   = blockIdx.y * 128;
    const int srow = lane >> 2;
    const int scol = (lane & 3) * 8;

    f32x4 acc[4][4];
    const f32x4 zz = {0.f, 0.f, 0.f, 0.f};
#pragma unroll
    for (int i = 0; i < 4; ++i)
#pragma unroll
        for (int j = 0; j < 4; ++j) acc[i][j] = zz;

    auto stage = [&](int k0, int p) {
#pragma unroll
        for (int c = 0; c < 2; ++c) {
            int u = w * 2 + c;
            gld_lds16(A  + (size_t)(m0 + u * 16 + srow) * K + k0 + scol, &As[p][u * 512]);
            gld_lds16(Bt + (size_t)(n0 + u * 16 + srow) * K + k0 + scol, &Bs[p][u * 512]);
        }
    };

    stage(0, 0);
    for (int j = 0; j < 32; ++j) {
        __syncthreads();
        if (j < 31) stage((j + 1) * 32, (j + 1) & 1);
        const int p = j & 1;
        bf16x8 af[4], bfr[4];
#pragma unroll
        for (int i = 0; i < 4; ++i)
            af[i] = *(const bf16x8*)&As[p][(wr * 64 + i * 16 + ln) * 32 + q * 8];
#pragma unroll
        for (int jj = 0; jj < 4; ++jj)
            bfr[jj] = *(const bf16x8*)&Bs[p][(wc * 64 + jj * 16 + ln) * 32 + q * 8];
#pragma unroll
        for (int i = 0; i < 4; ++i)
#pragma unroll
            for (int jj = 0; jj < 4; ++jj)
                acc[i][jj] = __builtin_amdgcn_mfma_f32_16x16x32_bf16(af[i], bfr[jj], acc[i][jj], 0, 0, 0);
    }

#pragma unroll
    for (int i = 0; i < 4; ++i) {
#pragma unroll
        for (int j = 0; j < 4; ++j) {
            f32x4 c = acc[i][j];
            int mb = m0 + wr * 64 + i * 16 + q * 4;
            int nn = n0 + wc * 64 + j * 16 + ln;
#pragma unroll
            for (int r = 0; r < 4; ++r) {
                int m = mb + r;
                float val = c[r] * a_scale;
                ((float*)dst)[(size_t)m * 1024 + nn] = val + bias[nn];
            }
        }
    }
}

// Flash attention, transposed-S, no online max (|s*log2e| bounded ~3).
// 64-key tiles, double-buffered K/V staging, ONE barrier per iter.
// Builtin exp2 (trans-op hazard safe); l-reduction deferred out of K-loop;
// P register-resident (16x16x16 PV); swizzled K/V LDS.
// S^T = K Q^T ; O^T = V^T P^T. Q pre-scaled by log2e/sqrt(E).
// Q,K [head][s][d]; Vt [head][d][s]. O bf16 [N,S,E]. grid (64 heads, 16 qt).
__global__ __launch_bounds__(256, 4)
void attn_kernel(const unsigned short* __restrict__ Q, const unsigned short* __restrict__ Kg,
                 const unsigned short* __restrict__ Vt, unsigned short* __restrict__ Og)
{
    __shared__ __align__(16) unsigned short Ks[2][4096];   // 2 x (2 panels of 64rows x 32)
    __shared__ __align__(16) unsigned short Vs[2][4096];   // 2 x (2 panels of 64d  x 32)

    const int t    = threadIdx.x;
    const int lane = t & 63;
    const int w    = t >> 6;
    const int q    = lane >> 4;
    const int ln   = lane & 15;
    const int xs   = (ln >> 1) & 3;      // read-side swizzle: slot ^= (row>>1)&3, row%16 = ln
    const int head = blockIdx.x;
    const int qt   = blockIdx.y;

    const unsigned short* Qh  = Q  + (size_t)head * 2048 * 64;
    const unsigned short* Kh  = Kg + (size_t)head * 2048 * 64;
    const unsigned short* Vth = Vt + (size_t)head * 64 * 2048;

    const int srow = lane >> 2;
    // staging writes are linear (lane*16B): row = lane>>2, phys slot = lane&3.
    // phys slot must hold logical slot (lane&3)^sw(row), sw(row)=(row>>1)&3=(lane>>3)&3
    const int ssw  = ((lane & 3) ^ ((lane >> 3) & 3)) * 8;

    // Q as B-fragments (qrow in lanes, k = d), resident all kernel
    bf16x8 qf[2][2];
    const int rowb = qt * 128 + w * 32;
#pragma unroll
    for (int ti = 0; ti < 2; ++ti)
#pragma unroll
        for (int kc = 0; kc < 2; ++kc)
            qf[ti][kc] = *(const bf16x8*)&Qh[(size_t)(rowb + ti * 16 + ln) * 64 + kc * 32 + q * 8];

    const f32x4 zz = {0.f, 0.f, 0.f, 0.f};
    f32x4 oa[2][4];
#pragma unroll
    for (int ti = 0; ti < 2; ++ti)
#pragma unroll
        for (int dt = 0; dt < 4; ++dt) oa[ti][dt] = zz;
    float l_s[2] = {0.f, 0.f};           // lane-partial; cross-q reduce deferred

    // stage 64-key tile j into buffer p (source column pre-swizzled)
    auto stage = [&](int j, int p) {
#pragma unroll
        for (int c = 0; c < 2; ++c) {
            int u = w * 2 + c;                 // 0..7
            int kc = u >> 2, rg = u & 3;
            gld_lds16(Kh + (size_t)(j * 64 + rg * 16 + srow) * 64 + kc * 32 + ssw,
                      &Ks[p][kc * 2048 + rg * 512]);
            gld_lds16(Vth + (size_t)(rg * 16 + srow) * 2048 + j * 64 + kc * 32 + ssw,
                      &Vs[p][kc * 2048 + rg * 512]);
        }
    };

    stage(0, 0);
    for (int j = 0; j < 32; ++j) {
        __syncthreads();                       // drains gld(j); all reads of buf (j+1)&1 done
        if (j < 31) stage(j + 1, (j + 1) & 1);
        const int p = j & 1;

        // ---- S^T = K Q^T, per 16-key tile; exp + cvt immediately (short sa life) ----
        bf16x4 pb[4][2];                       // P^T B-fragments, in registers
        float rs0 = 0.f, rs1 = 0.f;
#pragma unroll
        for (int kt = 0; kt < 4; ++kt) {
            f32x4 s0 = zz, s1 = zz;
#pragma unroll
            for (int kc = 0; kc < 2; ++kc) {
                bf16x8 ka = *(const bf16x8*)&Ks[p][kc * 2048 + (kt * 16 + ln) * 32 + ((q ^ xs) * 8)];
                s0 = __builtin_amdgcn_mfma_f32_16x16x32_bf16(ka, qf[0][kc], s0, 0, 0, 0);
                s1 = __builtin_amdgcn_mfma_f32_16x16x32_bf16(ka, qf[1][kc], s1, 0, 0, 0);
            }
            {
                float a0 = fexp2(s0[0]), a1 = fexp2(s0[1]), a2 = fexp2(s0[2]), a3 = fexp2(s0[3]);
                rs0 += (a0 + a1) + (a2 + a3);
                f32x4 pe = {a0, a1, a2, a3};
                pb[kt][0] = __builtin_convertvector(pe, bf16x4);
            }
            {
                float b0 = fexp2(s1[0]), b1 = fexp2(s1[1]), b2 = fexp2(s1[2]), b3 = fexp2(s1[3]);
                rs1 += (b0 + b1) + (b2 + b3);
                f32x4 pe = {b0, b1, b2, b3};
                pb[kt][1] = __builtin_convertvector(pe, bf16x4);
            }
        }
        l_s[0] += rs0;
        l_s[1] += rs1;

        // ---- O^T += V^T P^T, K=16 MFMAs, P from registers ----
#pragma unroll
        for (int kt = 0; kt < 4; ++kt) {
            const int kc = kt >> 1;
            // V^T 8B read: keys kt*16 + q*4 .. +3 -> 16B slot s=(kt&1)*2+(q>>1), half q&1
            const int so = ((((kt & 1) * 2 + (q >> 1)) ^ xs) * 8) + (q & 1) * 4;
            bf16x4 va[4];
#pragma unroll
            for (int dt = 0; dt < 4; ++dt)
                va[dt] = *(const bf16x4*)&Vs[p][kc * 2048 + (dt * 16 + ln) * 32 + so];
#pragma unroll
            for (int dt = 0; dt < 4; ++dt) {
                oa[0][dt] = mfma16(va[dt], pb[kt][0], oa[0][dt]);
                oa[1][dt] = mfma16(va[dt], pb[kt][1], oa[1][dt]);
            }
        }
    }

    // deferred cross-q reduction (lanes differ in bits 4,5 of lane id)
    l_s[0] += __shfl_xor(l_s[0], 16); l_s[0] += __shfl_xor(l_s[0], 32);
    l_s[1] += __shfl_xor(l_s[1], 16); l_s[1] += __shfl_xor(l_s[1], 32);

    // ---- finalize: O = (O^T)^T / l, packed 8B stores ----
    const int n = head >> 4;
    const int hbase = (head & 15) * 64;
#pragma unroll
    for (int ti = 0; ti < 2; ++ti) {
        float inv = 1.f / l_s[ti];
        int sr = qt * 128 + w * 32 + ti * 16 + ln;
        size_t base = ((size_t)n * 2048 + sr) * 1024 + hbase;
#pragma unroll
        for (int dt = 0; dt < 4; ++dt) {
            uint2 pk;
            pk.x = pkbf(oa[ti][dt][0] * inv, oa[ti][dt][1] * inv);
            pk.y = pkbf(oa[ti][dt][2] * inv, oa[ti][dt][3] * inv);
            *(uint2*)&Og[base + dt * 16 + q * 4] = pk;
        }
    }
}

extern "C" void kernel_launch(void* const* d_in, const int* in_sizes, int n_in,
                              void* d_out, int out_size, void* d_ws, size_t ws_size,
                              hipStream_t stream)
{
    (void)in_sizes; (void)n_in; (void)out_size; (void)ws_size;
    const float* values  = (const float*)d_in[0];
    const float* keys    = (const float*)d_in[1];
    const float* queries = (const float*)d_in[2];
    const float* Wv = (const float*)d_in[3];
    const float* Wk = (const float*)d_in[4];
    const float* Wq = (const float*)d_in[5];
    const float* Wo = (const float*)d_in[6];
    const float* bo = (const float*)d_in[7];
    float* out = (float*)d_out;

    unsigned short* ws   = (unsigned short*)d_ws;
    unsigned short* Wo_b = ws + 3145728;          // weights: ws + z*1M (z=0..2), Wo at 3M
    unsigned short* Ob   = ws + 4194304;          // 8M: attn output
    unsigned short* Qb   = ws + 12582912;         // 8M each
    unsigned short* Kb   = Qb + 8388608;
    unsigned short* Vtb  = Kb + 8388608;          // total 36M shorts = 72 MB

    const float qscale = 1.4426950408889634f / 32.f;   // log2(e)/sqrt(E)
    dim3 b(256);

    cast4_kernel<<<4096, b, 0, stream>>>(Wv, Wk, Wq, Wo, ws);
    gemm_qkv<<<dim3(64, 8, 3), b, 0, stream>>>(values, keys, queries, ws, Vtb, Kb, Qb, qscale);
    attn_kernel<<<dim3(64, 16), b, 0, stream>>>(Qb, Kb, Vtb, Ob);
    gemm_bt<2><<<dim3(64, 8), b, 0, stream>>>(Ob, Wo_b, out, bo, 1.f);
}